// Round 2
// baseline (6198.692 us; speedup 1.0000x reference)
//
#include <hip/hip_runtime.h>
#include <cstdint>
#include <cmath>

#define B_ 256
#define T_ 16
#define V_ 32000
#define E_ 256
#define H_ 512

// ---------------- Threefry-2x32 (JAX-compatible) ----------------
__device__ __forceinline__ uint32_t rotl32(uint32_t x, int r) {
  return (x << r) | (x >> (32 - r));
}

__device__ __forceinline__ void tf2x32(uint32_t k0, uint32_t k1, uint32_t x0, uint32_t x1,
                                       uint32_t& o0, uint32_t& o1) {
  uint32_t k2 = k0 ^ k1 ^ 0x1BD11BDAu;
  x0 += k0; x1 += k1;
#define TFR(r) { x0 += x1; x1 = rotl32(x1, (r)); x1 ^= x0; }
  TFR(13) TFR(15) TFR(26) TFR(6)   x0 += k1; x1 += k2 + 1u;
  TFR(17) TFR(29) TFR(16) TFR(24)  x0 += k2; x1 += k0 + 2u;
  TFR(13) TFR(15) TFR(26) TFR(6)   x0 += k0; x1 += k1 + 3u;
  TFR(17) TFR(29) TFR(16) TFR(24)  x0 += k1; x1 += k2 + 4u;
  TFR(13) TFR(15) TFR(26) TFR(6)   x0 += k2; x1 += k0 + 5u;
#undef TFR
  o0 = x0; o1 = x1;
}

__device__ __forceinline__ float gumbel_from_bits(uint32_t bits) {
  uint32_t man = bits >> 9;
  float u;
  if (man == 0u) u = 1.17549435e-38f;
  else u = __uint_as_float(man | 0x3f800000u) - 1.0f;
  float inner = (float)log((double)u);            // < 0
  float outer = (float)log((double)(-inner));
  return -outer;
}

// ---------------- prep: interleaved (j,gate) weights, bias sums, step keys ----------------
__global__ __launch_bounds__(256) void prep_kernel(
    const float* __restrict__ wih0, const float* __restrict__ whh0,
    const float* __restrict__ wih1, const float* __restrict__ whh1,
    const float* __restrict__ bih0, const float* __restrict__ bhh0,
    const float* __restrict__ bih1, const float* __restrict__ bhh1,
    float* __restrict__ wq0, float* __restrict__ wq1,
    float* __restrict__ bq0, float* __restrict__ bq1, uint32_t* __restrict__ keys)
{
  const long long stride = (long long)gridDim.x * blockDim.x;
  const long long i0 = (long long)blockIdx.x * blockDim.x + threadIdx.x;
  if (i0 < 16) {
    uint32_t o0, o1;
    tf2x32(0u, 1u, 0u, (uint32_t)i0, o0, o1);   // split(key(1), 16)
    keys[2 * i0] = o0; keys[2 * i0 + 1] = o1;
  }
  const long long N0 = 2048LL * 768, N1 = 2048LL * 1024;
  const long long TOT = N0 + N1 + 2048 + 2048;
  for (long long i = i0; i < TOT; i += stride) {
    if (i < N0) {
      int n = (int)(i / 768), k = (int)(i % 768);
      int j = n >> 2, g = n & 3;
      int r = g * 512 + j;
      wq0[i] = (k < 256) ? wih0[r * 256 + k] : whh0[r * 512 + (k - 256)];
    } else if (i < N0 + N1) {
      long long q = i - N0;
      int n = (int)(q / 1024), k = (int)(q % 1024);
      int j = n >> 2, g = n & 3;
      int r = g * 512 + j;
      wq1[q] = (k < 512) ? wih1[r * 512 + k] : whh1[r * 512 + (k - 512)];
    } else if (i < N0 + N1 + 2048) {
      int n = (int)(i - N0 - N1);
      int j = n >> 2, g = n & 3;
      bq0[n] = bih0[g * 512 + j] + bhh0[g * 512 + j];
    } else {
      int n = (int)(i - N0 - N1 - 2048);
      int j = n >> 2, g = n & 3;
      bq1[n] = bih1[g * 512 + j] + bhh1[g * 512 + j];
    }
  }
}

// ---------------- backbone: Linear + LayerNorm + exact GELU, state init ----------------
__global__ __launch_bounds__(256) void backbone_kernel(
    const float* __restrict__ x, const float* __restrict__ bb_w, const float* __restrict__ bb_b,
    const float* __restrict__ ln_g, const float* __restrict__ ln_b, const float* __restrict__ sos,
    float* __restrict__ xh0, float* __restrict__ xh1,
    float* __restrict__ c0, float* __restrict__ c1, int* __restrict__ done)
{
  const int b = blockIdx.x, tid = threadIdx.x;
  __shared__ float xs[E_];
  __shared__ float zs[H_];
  __shared__ float red[256];
  xs[tid] = x[b * E_ + tid];
  __syncthreads();
  for (int jj = 0; jj < 2; ++jj) {
    int j = jj * 256 + tid;
    float acc = 0.0f;
#pragma unroll 4
    for (int k = 0; k < E_; ++k) acc = fmaf(xs[k], bb_w[(size_t)j * E_ + k], acc);
    zs[j] = acc + bb_b[j];
  }
  __syncthreads();
  red[tid] = zs[tid] + zs[tid + 256];
  __syncthreads();
  for (int off = 128; off > 0; off >>= 1) { if (tid < off) red[tid] += red[tid + off]; __syncthreads(); }
  const float mu = red[0] / 512.0f;
  __syncthreads();
  {
    float d0 = zs[tid] - mu, d1 = zs[tid + 256] - mu;
    red[tid] = d0 * d0 + d1 * d1;
  }
  __syncthreads();
  for (int off = 128; off > 0; off >>= 1) { if (tid < off) red[tid] += red[tid + off]; __syncthreads(); }
  const float var = red[0] / 512.0f;
  const float sv = sqrtf(var + 1e-5f);
  for (int jj = 0; jj < 2; ++jj) {
    int j = jj * 256 + tid;
    float zn = (zs[j] - mu) / sv * ln_g[j] + ln_b[j];
    float h = 0.5f * zn * (1.0f + erff(zn / 1.41421356237309515f));
    xh0[(size_t)b * 768 + 256 + j] = h;        // h0 for step 0 cell0
    xh1[(size_t)b * 1024 + 512 + j] = 0.0f;    // h1 init
    c0[(size_t)b * 512 + j] = 0.0f;
    c1[(size_t)b * 512 + j] = 0.0f;
  }
  xh0[(size_t)b * 768 + tid] = sos[tid];       // inp init = sos
  if (tid == 0) done[b] = 0;
}

// ---------------- fused cell GEMM + LSTM update (TN must be 4: one hidden/thread) ----------
template<int MT, int NT, int TM, int TN>
__global__ __launch_bounds__(256) void gemm_lstm(
    const float* __restrict__ A, int lda,
    const float* __restrict__ W, int ldw,
    const float* __restrict__ bias,
    float* __restrict__ c,
    float* __restrict__ dA, int ldA,
    float* __restrict__ dB, int ldB, int K)
{
  constexpr int KT = 16;
  __shared__ float As[KT][MT + 4];
  __shared__ float Ws[KT][NT + 4];
  const int tid = threadIdx.x;
  constexpr int NX = NT / TN;
  const int tx = tid % NX;
  const int ty = tid / NX;
  const int m0 = blockIdx.y * MT;
  const int n0 = blockIdx.x * NT;

  float acc[TM][TN];
#pragma unroll
  for (int i = 0; i < TM; ++i)
#pragma unroll
    for (int j = 0; j < TN; ++j) acc[i][j] = 0.0f;

  for (int kt = 0; kt < K; kt += KT) {
    __syncthreads();
    for (int e = tid; e < MT * KT / 4; e += 256) {
      int row = e / (KT / 4), kq = (e % (KT / 4)) * 4;
      float4 v = *(const float4*)&A[(size_t)(m0 + row) * lda + kt + kq];
      As[kq + 0][row] = v.x; As[kq + 1][row] = v.y;
      As[kq + 2][row] = v.z; As[kq + 3][row] = v.w;
    }
    for (int e = tid; e < NT * KT / 4; e += 256) {
      int row = e / (KT / 4), kq = (e % (KT / 4)) * 4;
      float4 v = *(const float4*)&W[(size_t)(n0 + row) * ldw + kt + kq];
      Ws[kq + 0][row] = v.x; Ws[kq + 1][row] = v.y;
      Ws[kq + 2][row] = v.z; Ws[kq + 3][row] = v.w;
    }
    __syncthreads();
#pragma unroll
    for (int k = 0; k < KT; ++k) {
      float a[TM], w[TN];
#pragma unroll
      for (int i = 0; i < TM; ++i) a[i] = As[k][ty * TM + i];
#pragma unroll
      for (int j = 0; j < TN; j += 4) *(float4*)&w[j] = *(const float4*)&Ws[k][tx * TN + j];
#pragma unroll
      for (int i = 0; i < TM; ++i)
#pragma unroll
        for (int j = 0; j < TN; ++j) acc[i][j] = fmaf(a[i], w[j], acc[i][j]);
    }
  }
  // LSTM epilogue: thread's 4 columns = gates i,f,g,o of hidden unit j
  const int n = n0 + tx * 4;
  const int j = n >> 2;
  const float b0 = bias[n], b1 = bias[n + 1], b2 = bias[n + 2], b3 = bias[n + 3];
#pragma unroll
  for (int i = 0; i < TM; ++i) {
    const int m = m0 + ty * TM + i;
    const float gi = acc[i][0] + b0;
    const float gf = acc[i][1] + b1;
    const float gg = acc[i][2] + b2;
    const float go = acc[i][3] + b3;
    const float si = 1.0f / (1.0f + expf(-gi));
    const float sf = 1.0f / (1.0f + expf(-gf));
    const float so = 1.0f / (1.0f + expf(-go));
    const float cn = sf * c[(size_t)m * 512 + j] + si * tanhf(gg);
    const float hn = so * tanhf(cn);
    c[(size_t)m * 512 + j] = cn;
    dA[(size_t)m * ldA + j] = hn;
    dB[(size_t)m * ldB + j] = hn;
  }
}

// ---------------- fused logits GEMM + gumbel argmax / softmax partials --------------------
template<int MT, int NT, int TM, int TN>
__global__ __launch_bounds__(256) void gemm_sample(
    const float* __restrict__ A, int lda,
    const float* __restrict__ W, int ldw,
    const float* __restrict__ bias,
    const uint32_t* __restrict__ keys, int t,
    float* __restrict__ partials, int K)
{
  constexpr int KT = 16;
  __shared__ float As[KT][MT + 4];
  __shared__ float Ws[KT][NT + 4];
  const int tid = threadIdx.x;
  constexpr int NX = NT / TN;
  const int tx = tid % NX;
  const int ty = tid / NX;
  const int m0 = blockIdx.y * MT;
  const int n0 = blockIdx.x * NT;

  float acc[TM][TN];
#pragma unroll
  for (int i = 0; i < TM; ++i)
#pragma unroll
    for (int j = 0; j < TN; ++j) acc[i][j] = 0.0f;

  for (int kt = 0; kt < K; kt += KT) {
    __syncthreads();
    for (int e = tid; e < MT * KT / 4; e += 256) {
      int row = e / (KT / 4), kq = (e % (KT / 4)) * 4;
      float4 v = *(const float4*)&A[(size_t)(m0 + row) * lda + kt + kq];
      As[kq + 0][row] = v.x; As[kq + 1][row] = v.y;
      As[kq + 2][row] = v.z; As[kq + 3][row] = v.w;
    }
    for (int e = tid; e < NT * KT / 4; e += 256) {
      int row = e / (KT / 4), kq = (e % (KT / 4)) * 4;
      float4 v = *(const float4*)&W[(size_t)(n0 + row) * ldw + kt + kq];
      Ws[kq + 0][row] = v.x; Ws[kq + 1][row] = v.y;
      Ws[kq + 2][row] = v.z; Ws[kq + 3][row] = v.w;
    }
    __syncthreads();
#pragma unroll
    for (int k = 0; k < KT; ++k) {
      float a[TM], w[TN];
#pragma unroll
      for (int i = 0; i < TM; i += 4) *(float4*)&a[i] = *(const float4*)&As[k][ty * TM + i];
#pragma unroll
      for (int j = 0; j < TN; j += 4) *(float4*)&w[j] = *(const float4*)&Ws[k][tx * TN + j];
#pragma unroll
      for (int i = 0; i < TM; ++i)
#pragma unroll
        for (int j = 0; j < TN; ++j) acc[i][j] = fmaf(a[i], w[j], acc[i][j]);
    }
  }
  // epilogue: per-row partials over this block's NT columns
  const uint32_t k0 = keys[2 * t], k1 = keys[2 * t + 1];
  const int nb = n0 + tx * TN;
  float bj[TN];
#pragma unroll
  for (int j = 0; j < TN; ++j) bj[j] = bias[nb + j];
  const int bn = blockIdx.x;
#pragma unroll
  for (int i = 0; i < TM; ++i) {
    const int m = m0 + ty * TM + i;
    float lmax = -INFINITY, sb = -INFINITY, lb = 0.0f; int ib = 0;
#pragma unroll
    for (int j = 0; j < TN; ++j) {
      float l = acc[i][j] + bj[j];
      uint32_t o0, o1;
      tf2x32(k0, k1, 0u, (uint32_t)(m * V_ + nb + j), o0, o1);
      float s = l + gumbel_from_bits(o0 ^ o1);
      lmax = fmaxf(lmax, l);
      if (s > sb) { sb = s; ib = nb + j; lb = l; }
    }
    // 16-lane (same-row) butterfly reduce, tie -> smaller index
    for (int o = 1; o < 16; o <<= 1) {
      float s2 = __shfl_xor(sb, o, 16);
      int   i2 = __shfl_xor(ib, o, 16);
      float l2 = __shfl_xor(lb, o, 16);
      if (s2 > sb || (s2 == sb && i2 < ib)) { sb = s2; ib = i2; lb = l2; }
      lmax = fmaxf(lmax, __shfl_xor(lmax, o, 16));
    }
    float S = 0.0f, Aa = 0.0f;
#pragma unroll
    for (int j = 0; j < TN; ++j) {
      float d = acc[i][j] + bj[j] - lmax;
      float e = expf(d);
      S += e; Aa = fmaf(e, d, Aa);
    }
    for (int o = 1; o < 16; o <<= 1) {
      S  += __shfl_xor(S, o, 16);
      Aa += __shfl_xor(Aa, o, 16);
    }
    if (tx == 0) {
      float* dst = partials + ((size_t)m * 250 + bn) * 8;
      *(float4*)dst       = make_float4(lmax, S, Aa, sb);
      *(float4*)(dst + 4) = make_float4(__int_as_float(ib), lb, 0.0f, 0.0f);
    }
  }
}

// ---------------- merge partials: token, logp, entropy, feedback ----------------
__global__ __launch_bounds__(256) void merge_sample(
    const float* __restrict__ partials, const float* __restrict__ emb,
    int t, int* __restrict__ done, float* __restrict__ xh0next,
    float* __restrict__ ids, float* __restrict__ logp, float* __restrict__ ent)
{
  const int b = blockIdx.x, tid = threadIdx.x;
  float M = -INFINITY, S = 0.0f, Aa = 0.0f, sb = -INFINITY, lb = 0.0f;
  int ib = 0x7fffffff;
  if (tid < 250) {
    const float* src = partials + ((size_t)b * 250 + tid) * 8;
    float4 p0 = *(const float4*)src;
    float4 p1 = *(const float4*)(src + 4);
    M = p0.x; S = p0.y; Aa = p0.z; sb = p0.w;
    ib = __float_as_int(p1.x); lb = p1.y;
  }
  __shared__ float sm[256], ss[256], sa[256], sv[256], sl[256];
  __shared__ int si[256];
  sm[tid] = M; __syncthreads();
  for (int o = 128; o > 0; o >>= 1) { if (tid < o) sm[tid] = fmaxf(sm[tid], sm[tid + o]); __syncthreads(); }
  const float Mg = sm[0];
  const float w = (S > 0.0f) ? expf(M - Mg) : 0.0f;
  ss[tid] = S * w;
  sa[tid] = (S > 0.0f) ? w * (Aa + (M - Mg) * S) : 0.0f;
  sv[tid] = sb; si[tid] = ib; sl[tid] = lb;
  __syncthreads();
  for (int o = 128; o > 0; o >>= 1) {
    if (tid < o) {
      ss[tid] += ss[tid + o]; sa[tid] += sa[tid + o];
      float v2 = sv[tid + o]; int i2 = si[tid + o];
      if (v2 > sv[tid] || (v2 == sv[tid] && i2 < si[tid])) {
        sv[tid] = v2; si[tid] = i2; sl[tid] = sl[tid + o];
      }
    }
    __syncthreads();
  }
  if (tid == 0) {
    const float Sg = ss[0], Ag = sa[0];
    const float logS = logf(Sg);
    const int tok = si[0];
    const float lp = sl[0] - Mg - logS;
    const float en = logS - Ag / Sg;
    const int dn = done[b];
    const int tokm = dn ? 0 : tok;
    ids[b * T_ + t]  = (float)tokm;
    logp[b * T_ + t] = dn ? 0.0f : lp;
    ent[b * T_ + t]  = dn ? 0.0f : en;
    done[b] = dn | (tokm == 0);
    si[0] = tokm;
  }
  __syncthreads();
  const int tk = si[0];
  xh0next[(size_t)b * 768 + tid] = emb[(size_t)tk * E_ + tid];
}

// ---------------- lengths + trailing-zero, then one-hot msg fill ----------------
__global__ void len_kernel(float* __restrict__ ids, float* __restrict__ lens) {
  const int b = threadIdx.x;  // 256 threads, 1 block
  int len = T_; bool has = false;
  for (int t = 0; t < T_; ++t) {
    if (!has && ids[b * T_ + t] == 0.0f) { has = true; len = t + 1; }
  }
  for (int t = len - 1; t < T_; ++t) ids[b * T_ + t] = 0.0f;
  lens[b] = (float)len;
}

__global__ __launch_bounds__(256) void msg_kernel(const float* __restrict__ ids,
                                                  float* __restrict__ msg) {
  const int bt = blockIdx.x;            // 4096 = B*T
  const int id = (int)ids[bt];
  float4* dst = (float4*)(msg + (size_t)bt * V_);
  for (int q = threadIdx.x; q < V_ / 4; q += 256) {
    const int v = q * 4;
    float4 val;
    val.x = (v     == id) ? 1.0f : 0.0f;
    val.y = (v + 1 == id) ? 1.0f : 0.0f;
    val.z = (v + 2 == id) ? 1.0f : 0.0f;
    val.w = (v + 3 == id) ? 1.0f : 0.0f;
    dst[q] = val;
  }
}

// ---------------- launcher ----------------
extern "C" void kernel_launch(void* const* d_in, const int* in_sizes, int n_in,
                              void* d_out, int out_size, void* d_ws, size_t ws_size,
                              hipStream_t stream) {
  const float* x    = (const float*)d_in[0];
  const float* bb_w = (const float*)d_in[1];
  const float* bb_b = (const float*)d_in[2];
  const float* ln_g = (const float*)d_in[3];
  const float* ln_b = (const float*)d_in[4];
  const float* emb  = (const float*)d_in[5];
  const float* sos  = (const float*)d_in[6];
  const float* wih0 = (const float*)d_in[7];
  const float* whh0 = (const float*)d_in[8];
  const float* bih0 = (const float*)d_in[9];
  const float* bhh0 = (const float*)d_in[10];
  const float* wih1 = (const float*)d_in[11];
  const float* whh1 = (const float*)d_in[12];
  const float* bih1 = (const float*)d_in[13];
  const float* bhh1 = (const float*)d_in[14];
  const float* out_w = (const float*)d_in[15];
  const float* out_b = (const float*)d_in[16];

  float* out  = (float*)d_out;
  float* ids  = out;                                  // [B,T]   4096
  float* msg  = out + 4096;                           // [B,T,V] 131072000
  float* logp = out + 131076096;                      // [B,T]   4096
  float* ent  = out + 131080192;                      // [B,T]   4096
  float* lens = out + 131084288;                      // [B]     256

  // scratch inside msg region (rewritten at the end)
  float* wq0  = msg;                                  // 1,572,864
  float* wq1  = wq0 + 1572864;                        // 2,097,152
  float* bq0  = wq1 + 2097152;                        // 2048
  float* bq1  = bq0 + 2048;                           // 2048
  float* xh0a = bq1 + 2048;                           // 196,608
  float* xh0b = xh0a + 196608;
  float* xh1a = xh0b + 196608;                        // 262,144
  float* xh1b = xh1a + 262144;
  float* h1b  = xh1b + 262144;                        // 131,072
  float* c0   = h1b + 131072;
  float* c1   = c0 + 131072;
  float* partials = c1 + 131072;                      // 256*250*8 = 512,000
  uint32_t* keys = (uint32_t*)(partials + 512000);    // 32
  int* done = (int*)(keys + 32);                      // 256

  prep_kernel<<<2048, 256, 0, stream>>>(wih0, whh0, wih1, whh1,
                                        bih0, bhh0, bih1, bhh1,
                                        wq0, wq1, bq0, bq1, keys);
  backbone_kernel<<<256, 256, 0, stream>>>(x, bb_w, bb_b, ln_g, ln_b, sos,
                                           xh0a, xh1a, c0, c1, done);
  for (int t = 0; t < T_; ++t) {
    float* x0c = (t & 1) ? xh0b : xh0a;
    float* x0n = (t & 1) ? xh0a : xh0b;
    float* x1c = (t & 1) ? xh1b : xh1a;
    float* x1n = (t & 1) ? xh1a : xh1b;
    // cell 0: reads [inp|h0], writes h0_new -> xh1 cur (first half) + xh0 next (+256)
    gemm_lstm<32, 64, 2, 4><<<dim3(32, 8), 256, 0, stream>>>(
        x0c, 768, wq0, 768, bq0, c0, x1c, 1024, x0n + 256, 768, 768);
    // cell 1: reads [h0_new|h1], writes h1_new -> h1b + xh1 next (+512)
    gemm_lstm<32, 64, 2, 4><<<dim3(32, 8), 256, 0, stream>>>(
        x1c, 1024, wq1, 1024, bq1, c1, h1b, 512, x1n + 512, 1024, 1024);
    // logits + fused sampling partials (no logits materialization)
    gemm_sample<128, 128, 8, 8><<<dim3(250, 2), 256, 0, stream>>>(
        h1b, 512, out_w, 512, out_b, keys, t, partials, 512);
    merge_sample<<<256, 256, 0, stream>>>(partials, emb, t, done, x0n,
                                          ids, logp, ent);
  }
  len_kernel<<<1, 256, 0, stream>>>(ids, lens);
  msg_kernel<<<4096, 256, 0, stream>>>(ids, msg);
}

// Round 3
// 3437.016 us; speedup vs baseline: 1.8035x; 1.8035x over previous
//
#include <hip/hip_runtime.h>
#include <cstdint>
#include <cmath>

#define B_ 256
#define T_ 16
#define V_ 32000
#define E_ 256
#define H_ 512

typedef __attribute__((ext_vector_type(8))) short bf16x8;
typedef __attribute__((ext_vector_type(4))) float f32x4;

// ---------------- Threefry-2x32 (JAX-compatible) ----------------
__device__ __forceinline__ uint32_t rotl32(uint32_t x, int r) {
  return (x << r) | (x >> (32 - r));
}

__device__ __forceinline__ void tf2x32(uint32_t k0, uint32_t k1, uint32_t x0, uint32_t x1,
                                       uint32_t& o0, uint32_t& o1) {
  uint32_t k2 = k0 ^ k1 ^ 0x1BD11BDAu;
  x0 += k0; x1 += k1;
#define TFR(r) { x0 += x1; x1 = rotl32(x1, (r)); x1 ^= x0; }
  TFR(13) TFR(15) TFR(26) TFR(6)   x0 += k1; x1 += k2 + 1u;
  TFR(17) TFR(29) TFR(16) TFR(24)  x0 += k2; x1 += k0 + 2u;
  TFR(13) TFR(15) TFR(26) TFR(6)   x0 += k0; x1 += k1 + 3u;
  TFR(17) TFR(29) TFR(16) TFR(24)  x0 += k1; x1 += k2 + 4u;
  TFR(13) TFR(15) TFR(26) TFR(6)   x0 += k2; x1 += k0 + 5u;
#undef TFR
  o0 = x0; o1 = x1;
}

__device__ __forceinline__ float gumbel_from_bits(uint32_t bits) {
  uint32_t man = bits >> 9;
  float u;
  if (man == 0u) u = 1.17549435e-38f;
  else u = __uint_as_float(man | 0x3f800000u) - 1.0f;
  float inner = (float)log((double)u);            // < 0
  float outer = (float)log((double)(-inner));
  return -outer;
}

// round f32 -> bf16 bits (RTNE), value assumed finite
__device__ __forceinline__ uint32_t f2bf(float x) {
  uint32_t u = __float_as_uint(x);
  return (u + 0x7fffu + ((u >> 16) & 1u)) >> 16;
}

// ---------------- prep: interleaved (j,gate) weights, bias sums, step keys ----------------
__global__ __launch_bounds__(256) void prep_kernel(
    const float* __restrict__ wih0, const float* __restrict__ whh0,
    const float* __restrict__ wih1, const float* __restrict__ whh1,
    const float* __restrict__ bih0, const float* __restrict__ bhh0,
    const float* __restrict__ bih1, const float* __restrict__ bhh1,
    float* __restrict__ wq0, float* __restrict__ wq1,
    float* __restrict__ bq0, float* __restrict__ bq1, uint32_t* __restrict__ keys)
{
  const long long stride = (long long)gridDim.x * blockDim.x;
  const long long i0 = (long long)blockIdx.x * blockDim.x + threadIdx.x;
  if (i0 < 16) {
    uint32_t o0, o1;
    tf2x32(0u, 1u, 0u, (uint32_t)i0, o0, o1);   // split(key(1), 16)
    keys[2 * i0] = o0; keys[2 * i0 + 1] = o1;
  }
  const long long N0 = 2048LL * 768, N1 = 2048LL * 1024;
  const long long TOT = N0 + N1 + 2048 + 2048;
  for (long long i = i0; i < TOT; i += stride) {
    if (i < N0) {
      int n = (int)(i / 768), k = (int)(i % 768);
      int j = n >> 2, g = n & 3;
      int r = g * 512 + j;
      wq0[i] = (k < 256) ? wih0[r * 256 + k] : whh0[r * 512 + (k - 256)];
    } else if (i < N0 + N1) {
      long long q = i - N0;
      int n = (int)(q / 1024), k = (int)(q % 1024);
      int j = n >> 2, g = n & 3;
      int r = g * 512 + j;
      wq1[q] = (k < 512) ? wih1[r * 512 + k] : whh1[r * 512 + (k - 512)];
    } else if (i < N0 + N1 + 2048) {
      int n = (int)(i - N0 - N1);
      int j = n >> 2, g = n & 3;
      bq0[n] = bih0[g * 512 + j] + bhh0[g * 512 + j];
    } else {
      int n = (int)(i - N0 - N1 - 2048);
      int j = n >> 2, g = n & 3;
      bq1[n] = bih1[g * 512 + j] + bhh1[g * 512 + j];
    }
  }
}

// ---------------- prep B2: out_w f32 [32000][512] -> bf16-split [32000][1536] = [hi|lo|hi] --
__global__ __launch_bounds__(256) void prepB2_kernel(const float* __restrict__ w,
                                                     ushort* __restrict__ B2)
{
  const long long stride = (long long)gridDim.x * blockDim.x;
  for (long long i = (long long)blockIdx.x * blockDim.x + threadIdx.x;
       i < (long long)V_ * 512; i += stride) {
    int n = (int)(i >> 9), k = (int)(i & 511);
    float x = w[i];
    uint32_t hi = f2bf(x);
    float hf = __uint_as_float(hi << 16);
    uint32_t lo = f2bf(x - hf);
    ushort* row = B2 + (size_t)n * 1536;
    row[k] = (ushort)hi;
    row[512 + k] = (ushort)lo;
    row[1024 + k] = (ushort)hi;
  }
}

// ---------------- backbone: Linear + LayerNorm + exact GELU, state init ----------------
__global__ __launch_bounds__(256) void backbone_kernel(
    const float* __restrict__ x, const float* __restrict__ bb_w, const float* __restrict__ bb_b,
    const float* __restrict__ ln_g, const float* __restrict__ ln_b, const float* __restrict__ sos,
    float* __restrict__ xh0, float* __restrict__ xh1,
    float* __restrict__ c0, float* __restrict__ c1, int* __restrict__ done)
{
  const int b = blockIdx.x, tid = threadIdx.x;
  __shared__ float xs[E_];
  __shared__ float zs[H_];
  __shared__ float red[256];
  xs[tid] = x[b * E_ + tid];
  __syncthreads();
  for (int jj = 0; jj < 2; ++jj) {
    int j = jj * 256 + tid;
    float acc = 0.0f;
#pragma unroll 4
    for (int k = 0; k < E_; ++k) acc = fmaf(xs[k], bb_w[(size_t)j * E_ + k], acc);
    zs[j] = acc + bb_b[j];
  }
  __syncthreads();
  red[tid] = zs[tid] + zs[tid + 256];
  __syncthreads();
  for (int off = 128; off > 0; off >>= 1) { if (tid < off) red[tid] += red[tid + off]; __syncthreads(); }
  const float mu = red[0] / 512.0f;
  __syncthreads();
  {
    float d0 = zs[tid] - mu, d1 = zs[tid + 256] - mu;
    red[tid] = d0 * d0 + d1 * d1;
  }
  __syncthreads();
  for (int off = 128; off > 0; off >>= 1) { if (tid < off) red[tid] += red[tid + off]; __syncthreads(); }
  const float var = red[0] / 512.0f;
  const float sv = sqrtf(var + 1e-5f);
  for (int jj = 0; jj < 2; ++jj) {
    int j = jj * 256 + tid;
    float zn = (zs[j] - mu) / sv * ln_g[j] + ln_b[j];
    float h = 0.5f * zn * (1.0f + erff(zn / 1.41421356237309515f));
    xh0[(size_t)b * 768 + 256 + j] = h;        // h0 for step 0 cell0
    xh1[(size_t)b * 1024 + 512 + j] = 0.0f;    // h1 init
    c0[(size_t)b * 512 + j] = 0.0f;
    c1[(size_t)b * 512 + j] = 0.0f;
  }
  xh0[(size_t)b * 768 + tid] = sos[tid];       // inp init = sos
  if (tid == 0) done[b] = 0;
}

// ---------------- fused cell GEMM + LSTM update (TN must be 4: one hidden/thread) ----------
template<int MT, int NT, int TM, int TN>
__global__ __launch_bounds__(256) void gemm_lstm(
    const float* __restrict__ A, int lda,
    const float* __restrict__ W, int ldw,
    const float* __restrict__ bias,
    float* __restrict__ c,
    float* __restrict__ dA, int ldA,
    float* __restrict__ dB, int ldB, int K)
{
  constexpr int KT = 16;
  __shared__ float As[KT][MT + 4];
  __shared__ float Ws[KT][NT + 4];
  const int tid = threadIdx.x;
  constexpr int NX = NT / TN;
  const int tx = tid % NX;
  const int ty = tid / NX;
  const int m0 = blockIdx.y * MT;
  const int n0 = blockIdx.x * NT;

  float acc[TM][TN];
#pragma unroll
  for (int i = 0; i < TM; ++i)
#pragma unroll
    for (int j = 0; j < TN; ++j) acc[i][j] = 0.0f;

  for (int kt = 0; kt < K; kt += KT) {
    __syncthreads();
    for (int e = tid; e < MT * KT / 4; e += 256) {
      int row = e / (KT / 4), kq = (e % (KT / 4)) * 4;
      float4 v = *(const float4*)&A[(size_t)(m0 + row) * lda + kt + kq];
      As[kq + 0][row] = v.x; As[kq + 1][row] = v.y;
      As[kq + 2][row] = v.z; As[kq + 3][row] = v.w;
    }
    for (int e = tid; e < NT * KT / 4; e += 256) {
      int row = e / (KT / 4), kq = (e % (KT / 4)) * 4;
      float4 v = *(const float4*)&W[(size_t)(n0 + row) * ldw + kt + kq];
      Ws[kq + 0][row] = v.x; Ws[kq + 1][row] = v.y;
      Ws[kq + 2][row] = v.z; Ws[kq + 3][row] = v.w;
    }
    __syncthreads();
#pragma unroll
    for (int k = 0; k < KT; ++k) {
      float a[TM], w[TN];
#pragma unroll
      for (int i = 0; i < TM; ++i) a[i] = As[k][ty * TM + i];
#pragma unroll
      for (int j = 0; j < TN; j += 4) *(float4*)&w[j] = *(const float4*)&Ws[k][tx * TN + j];
#pragma unroll
      for (int i = 0; i < TM; ++i)
#pragma unroll
        for (int j = 0; j < TN; ++j) acc[i][j] = fmaf(a[i], w[j], acc[i][j]);
    }
  }
  // LSTM epilogue: thread's 4 columns = gates i,f,g,o of hidden unit j
  const int n = n0 + tx * 4;
  const int j = n >> 2;
  const float b0 = bias[n], b1 = bias[n + 1], b2 = bias[n + 2], b3 = bias[n + 3];
#pragma unroll
  for (int i = 0; i < TM; ++i) {
    const int m = m0 + ty * TM + i;
    const float gi = acc[i][0] + b0;
    const float gf = acc[i][1] + b1;
    const float gg = acc[i][2] + b2;
    const float go = acc[i][3] + b3;
    const float si = 1.0f / (1.0f + expf(-gi));
    const float sf = 1.0f / (1.0f + expf(-gf));
    const float so = 1.0f / (1.0f + expf(-go));
    const float cn = sf * c[(size_t)m * 512 + j] + si * tanhf(gg);
    const float hn = so * tanhf(cn);
    c[(size_t)m * 512 + j] = cn;
    dA[(size_t)m * ldA + j] = hn;
    dB[(size_t)m * ldB + j] = hn;
  }
}

// ---------------- h1b f32 -> A2 bf16-split [256][1536] = [hi|hi|lo] ----------------
__global__ __launch_bounds__(256) void cvtA_kernel(const float* __restrict__ h,
                                                   ushort* __restrict__ A2)
{
  const int b = blockIdx.x;
  for (int k = threadIdx.x; k < 512; k += 256) {
    float x = h[(size_t)b * 512 + k];
    uint32_t hi = f2bf(x);
    float hf = __uint_as_float(hi << 16);
    uint32_t lo = f2bf(x - hf);
    ushort* row = A2 + (size_t)b * 1536;
    row[k] = (ushort)hi;
    row[512 + k] = (ushort)hi;
    row[1024 + k] = (ushort)lo;
  }
}

// ---------------- bf16 MFMA logits GEMM: [256][1536] x [32000][1536]^T + bias -> f32 -------
// 128x128 tile, BK=64, 4 waves (2x2), 4x4 frags of 16x16x32. XOR-swizzled LDS:
// LDS[row][kb'] (16B blocks) holds global block kb' ^ (row&7); staged via
// global_load_lds with pre-swizzled per-lane source (linear LDS dest).
typedef const __attribute__((address_space(1))) void* as1_t;
typedef __attribute__((address_space(3))) void* as3_t;
__device__ __forceinline__ void glds16(const void* g, void* l) {
  __builtin_amdgcn_global_load_lds((as1_t)g, (as3_t)l, 16, 0, 0);
}

__global__ __launch_bounds__(256) void mfma_logits(
    const ushort* __restrict__ A2,   // [256][1536] bf16
    const ushort* __restrict__ B2,   // [32000][1536] bf16
    const float* __restrict__ bias,  // [32000]
    float* __restrict__ logits)      // [256][32000] f32
{
  __shared__ ushort lds[16384];      // 32 KB: A tile [128][64] @0, B tile @16KB
  const int tid = threadIdx.x;
  const int lane = tid & 63;
  const int wid = tid >> 6;
  const int wm = wid >> 1, wn = wid & 1;
  const int m0 = blockIdx.y * 128;
  const int n0 = blockIdx.x * 128;

  f32x4 acc[4][4];
#pragma unroll
  for (int i = 0; i < 4; ++i)
#pragma unroll
    for (int j = 0; j < 4; ++j)
#pragma unroll
      for (int q = 0; q < 4; ++q) acc[i][j][q] = 0.0f;

  for (int kc = 0; kc < 24; ++kc) {
    __syncthreads();
    const int kus = kc * 64;                       // k offset in ushort units
#pragma unroll
    for (int s = 0; s < 4; ++s) {
      const int o = (wid * 4 + s) * 1024 + lane * 16;   // byte offset in tile
      const int row = o >> 7;
      const int kb = (o >> 4) & 7;
      const int ksrc = kus + ((kb ^ (row & 7)) << 3);   // ushort offset within row
      glds16(A2 + (size_t)(m0 + row) * 1536 + ksrc,
             (void*)((char*)lds + (wid * 4 + s) * 1024));
      glds16(B2 + (size_t)(n0 + row) * 1536 + ksrc,
             (void*)((char*)lds + 16384 + (wid * 4 + s) * 1024));
    }
    asm volatile("s_waitcnt vmcnt(0)" ::: "memory");
    __syncthreads();
#pragma unroll
    for (int ks = 0; ks < 2; ++ks) {
      bf16x8 a[4], b[4];
      const int kb = ks * 4 + (lane >> 4);
#pragma unroll
      for (int i = 0; i < 4; ++i) {
        const int row = wm * 64 + i * 16 + (lane & 15);
        a[i] = *(const bf16x8*)((const char*)lds + row * 128 + ((kb ^ (row & 7)) << 4));
        const int col = wn * 64 + i * 16 + (lane & 15);
        b[i] = *(const bf16x8*)((const char*)lds + 16384 + col * 128 + ((kb ^ (col & 7)) << 4));
      }
#pragma unroll
      for (int i = 0; i < 4; ++i)
#pragma unroll
        for (int j = 0; j < 4; ++j)
          acc[i][j] = __builtin_amdgcn_mfma_f32_16x16x32_bf16(a[i], b[j], acc[i][j], 0, 0, 0);
    }
  }
  float bj[4];
#pragma unroll
  for (int j = 0; j < 4; ++j) bj[j] = bias[n0 + wn * 64 + j * 16 + (lane & 15)];
  const int rbase = (lane >> 4) * 4;
#pragma unroll
  for (int i = 0; i < 4; ++i) {
    const int m = m0 + wm * 64 + i * 16 + rbase;
#pragma unroll
    for (int j = 0; j < 4; ++j) {
      const int n = n0 + wn * 64 + j * 16 + (lane & 15);
#pragma unroll
      for (int q = 0; q < 4; ++q)
        logits[(size_t)(m + q) * V_ + n] = acc[i][j][q] + bj[j];
    }
  }
}

// ---------------- sampling partials: 1 pass over logits, full occupancy ----------------
// grid (8 chunks of 4000, 256 rows); per (b,c): lmax, S, A (local max), best gumbel triple
__global__ __launch_bounds__(256) void sampleP(
    const float* __restrict__ logits, const uint32_t* __restrict__ keys, int t,
    float* __restrict__ partials)
{
  const int c = blockIdx.x, b = blockIdx.y, tid = threadIdx.x;
  const uint32_t k0 = keys[2 * t], k1 = keys[2 * t + 1];
  const int v0 = c * 4000;
  const float* lrow = logits + (size_t)b * V_ + v0;

  float lmax = -INFINITY, sb = -INFINITY, lb = 0.0f; int ib = 0;
  for (int idx = tid; idx < 1000; idx += 256) {
    float4 l4 = *(const float4*)&lrow[idx * 4];
    const float le[4] = {l4.x, l4.y, l4.z, l4.w};
#pragma unroll
    for (int e = 0; e < 4; ++e) {
      const int v = v0 + idx * 4 + e;
      uint32_t o0, o1;
      tf2x32(k0, k1, 0u, (uint32_t)(b * V_ + v), o0, o1);
      const float s = le[e] + gumbel_from_bits(o0 ^ o1);
      lmax = fmaxf(lmax, le[e]);
      if (s > sb) { sb = s; ib = v; lb = le[e]; }
    }
  }
  __shared__ float sm[256], sv[256], sl[256];
  __shared__ int si[256];
  sm[tid] = lmax; sv[tid] = sb; si[tid] = ib; sl[tid] = lb;
  __syncthreads();
  for (int o = 128; o > 0; o >>= 1) {
    if (tid < o) {
      sm[tid] = fmaxf(sm[tid], sm[tid + o]);
      float v2 = sv[tid + o]; int i2 = si[tid + o];
      if (v2 > sv[tid] || (v2 == sv[tid] && i2 < si[tid])) {
        sv[tid] = v2; si[tid] = i2; sl[tid] = sl[tid + o];
      }
    }
    __syncthreads();
  }
  const float m = sm[0];
  float S = 0.0f, Aa = 0.0f;
  for (int idx = tid; idx < 1000; idx += 256) {
    float4 l4 = *(const float4*)&lrow[idx * 4];
    const float le[4] = {l4.x, l4.y, l4.z, l4.w};
#pragma unroll
    for (int e = 0; e < 4; ++e) {
      const float d = le[e] - m;
      const float ex = expf(d);
      S += ex; Aa = fmaf(ex, d, Aa);
    }
  }
  __shared__ float ss[256], sa[256];
  ss[tid] = S; sa[tid] = Aa;
  __syncthreads();
  for (int o = 128; o > 0; o >>= 1) {
    if (tid < o) { ss[tid] += ss[tid + o]; sa[tid] += sa[tid + o]; }
    __syncthreads();
  }
  if (tid == 0) {
    float* dst = partials + ((size_t)b * 8 + c) * 8;
    *(float4*)dst       = make_float4(m, ss[0], sa[0], sv[0]);
    *(float4*)(dst + 4) = make_float4(__int_as_float(si[0]), sl[0], 0.0f, 0.0f);
  }
}

// ---------------- merge partials: token, logp, entropy, feedback ----------------
__global__ __launch_bounds__(256) void merge_sample(
    const float* __restrict__ partials, const float* __restrict__ emb,
    int t, int* __restrict__ done, float* __restrict__ xh0next,
    float* __restrict__ ids, float* __restrict__ logp, float* __restrict__ ent)
{
  const int b = blockIdx.x, tid = threadIdx.x;
  float M = -INFINITY, S = 0.0f, Aa = 0.0f, sb = -INFINITY, lb = 0.0f;
  int ib = 0x7fffffff;
  if (tid < 8) {
    const float* src = partials + ((size_t)b * 8 + tid) * 8;
    float4 p0 = *(const float4*)src;
    float4 p1 = *(const float4*)(src + 4);
    M = p0.x; S = p0.y; Aa = p0.z; sb = p0.w;
    ib = __float_as_int(p1.x); lb = p1.y;
  }
  __shared__ float sm[256], ss[256], sa[256], sv[256], sl[256];
  __shared__ int si[256];
  sm[tid] = M; __syncthreads();
  for (int o = 128; o > 0; o >>= 1) { if (tid < o) sm[tid] = fmaxf(sm[tid], sm[tid + o]); __syncthreads(); }
  const float Mg = sm[0];
  const float w = (S > 0.0f) ? expf(M - Mg) : 0.0f;
  ss[tid] = S * w;
  sa[tid] = (S > 0.0f) ? w * (Aa + (M - Mg) * S) : 0.0f;
  sv[tid] = sb; si[tid] = ib; sl[tid] = lb;
  __syncthreads();
  for (int o = 128; o > 0; o >>= 1) {
    if (tid < o) {
      ss[tid] += ss[tid + o]; sa[tid] += sa[tid + o];
      float v2 = sv[tid + o]; int i2 = si[tid + o];
      if (v2 > sv[tid] || (v2 == sv[tid] && i2 < si[tid])) {
        sv[tid] = v2; si[tid] = i2; sl[tid] = sl[tid + o];
      }
    }
    __syncthreads();
  }
  if (tid == 0) {
    const float Sg = ss[0], Ag = sa[0];
    const float logS = logf(Sg);
    const int tok = si[0];
    const float lp = sl[0] - Mg - logS;
    const float en = logS - Ag / Sg;
    const int dn = done[b];
    const int tokm = dn ? 0 : tok;
    ids[b * T_ + t]  = (float)tokm;
    logp[b * T_ + t] = dn ? 0.0f : lp;
    ent[b * T_ + t]  = dn ? 0.0f : en;
    done[b] = dn | (tokm == 0);
    si[0] = tokm;
  }
  __syncthreads();
  const int tk = si[0];
  xh0next[(size_t)b * 768 + tid] = emb[(size_t)tk * E_ + tid];
}

// ---------------- lengths + trailing-zero, then one-hot msg fill ----------------
__global__ void len_kernel(float* __restrict__ ids, float* __restrict__ lens) {
  const int b = threadIdx.x;  // 256 threads, 1 block
  int len = T_; bool has = false;
  for (int t = 0; t < T_; ++t) {
    if (!has && ids[b * T_ + t] == 0.0f) { has = true; len = t + 1; }
  }
  for (int t = len - 1; t < T_; ++t) ids[b * T_ + t] = 0.0f;
  lens[b] = (float)len;
}

__global__ __launch_bounds__(256) void msg_kernel(const float* __restrict__ ids,
                                                  float* __restrict__ msg) {
  const int bt = blockIdx.x;            // 4096 = B*T
  const int id = (int)ids[bt];
  float4* dst = (float4*)(msg + (size_t)bt * V_);
  for (int q = threadIdx.x; q < V_ / 4; q += 256) {
    const int v = q * 4;
    float4 val;
    val.x = (v     == id) ? 1.0f : 0.0f;
    val.y = (v + 1 == id) ? 1.0f : 0.0f;
    val.z = (v + 2 == id) ? 1.0f : 0.0f;
    val.w = (v + 3 == id) ? 1.0f : 0.0f;
    dst[q] = val;
  }
}

// ---------------- launcher ----------------
extern "C" void kernel_launch(void* const* d_in, const int* in_sizes, int n_in,
                              void* d_out, int out_size, void* d_ws, size_t ws_size,
                              hipStream_t stream) {
  const float* x    = (const float*)d_in[0];
  const float* bb_w = (const float*)d_in[1];
  const float* bb_b = (const float*)d_in[2];
  const float* ln_g = (const float*)d_in[3];
  const float* ln_b = (const float*)d_in[4];
  const float* emb  = (const float*)d_in[5];
  const float* sos  = (const float*)d_in[6];
  const float* wih0 = (const float*)d_in[7];
  const float* whh0 = (const float*)d_in[8];
  const float* bih0 = (const float*)d_in[9];
  const float* bhh0 = (const float*)d_in[10];
  const float* wih1 = (const float*)d_in[11];
  const float* whh1 = (const float*)d_in[12];
  const float* bih1 = (const float*)d_in[13];
  const float* bhh1 = (const float*)d_in[14];
  const float* out_w = (const float*)d_in[15];
  const float* out_b = (const float*)d_in[16];

  float* out  = (float*)d_out;
  float* ids  = out;                                  // [B,T]   4096
  float* msg  = out + 4096;                           // [B,T,V] 131072000
  float* logp = out + 131076096;                      // [B,T]   4096
  float* ent  = out + 131080192;                      // [B,T]   4096
  float* lens = out + 131084288;                      // [B]     256

  // scratch inside msg region (rewritten at the end)
  float* p = msg;
  float* wq0  = p; p += 1572864;
  float* wq1  = p; p += 2097152;
  float* bq0  = p; p += 2048;
  float* bq1  = p; p += 2048;
  float* xh0a = p; p += 196608;
  float* xh0b = p; p += 196608;
  float* xh1a = p; p += 262144;
  float* xh1b = p; p += 262144;
  float* h1b  = p; p += 131072;
  float* c0   = p; p += 131072;
  float* c1   = p; p += 131072;
  float* partials = p; p += 16384;
  uint32_t* keys = (uint32_t*)p; p += 64;
  int* done = (int*)p; p += 256;
  ushort* A2 = (ushort*)p; p += 196608;               // 256*1536 bf16
  ushort* B2 = (ushort*)p; p += 24576000;             // 32000*1536 bf16
  float* logits = p; p += 8192000;                    // 256*32000 f32

  prep_kernel<<<2048, 256, 0, stream>>>(wih0, whh0, wih1, whh1,
                                        bih0, bhh0, bih1, bhh1,
                                        wq0, wq1, bq0, bq1, keys);
  prepB2_kernel<<<4096, 256, 0, stream>>>(out_w, B2);
  backbone_kernel<<<256, 256, 0, stream>>>(x, bb_w, bb_b, ln_g, ln_b, sos,
                                           xh0a, xh1a, c0, c1, done);
  for (int t = 0; t < T_; ++t) {
    float* x0c = (t & 1) ? xh0b : xh0a;
    float* x0n = (t & 1) ? xh0a : xh0b;
    float* x1c = (t & 1) ? xh1b : xh1a;
    float* x1n = (t & 1) ? xh1a : xh1b;
    gemm_lstm<32, 64, 2, 4><<<dim3(32, 8), 256, 0, stream>>>(
        x0c, 768, wq0, 768, bq0, c0, x1c, 1024, x0n + 256, 768, 768);
    gemm_lstm<32, 64, 2, 4><<<dim3(32, 8), 256, 0, stream>>>(
        x1c, 1024, wq1, 1024, bq1, c1, h1b, 512, x1n + 512, 1024, 1024);
    cvtA_kernel<<<256, 256, 0, stream>>>(h1b, A2);
    mfma_logits<<<dim3(250, 2), 256, 0, stream>>>(A2, B2, out_b, logits);
    sampleP<<<dim3(8, 256), 256, 0, stream>>>(logits, keys, t, partials);
    merge_sample<<<256, 256, 0, stream>>>(partials, emb, t, done, x0n,
                                          ids, logp, ent);
  }
  len_kernel<<<1, 256, 0, stream>>>(ids, lens);
  msg_kernel<<<4096, 256, 0, stream>>>(ids, msg);
}